// Round 1
// baseline (132.637 us; speedup 1.0000x reference)
//
#include <hip/hip_runtime.h>

// Problem constants (match reference)
#define NB 32
#define CH 3
#define HH 768
#define WW 768

// Tiling
#define TW 64           // output tile width
#define TH 32           // output tile height
#define HALO_W (TW + 4) // 68
#define HALO_H (TH + 4) // 36
#define RX 4            // outputs per thread in w (float4 stores)
#define RY 2            // outputs per thread in h
// 256 threads = 16 across (64/4) x 16 down (32/2)

__global__ __launch_bounds__(256) void colwarp_conv_kernel(
    const float* __restrict__ im,
    const float* __restrict__ flat,
    float* __restrict__ out)
{
    const int tilesW = WW / TW;                 // 12
    const int tile   = blockIdx.x;              // 0..(12*24-1)
    const int b      = blockIdx.y;              // 0..31
    const int tw0    = (tile % tilesW) * TW;
    const int th0    = (tile / tilesW) * TH;

    // 3 * 36 * 68 * 4B = 29376 B LDS -> 5 blocks/CU possible
    __shared__ float xs[CH][HALO_H][HALO_W];

    const int tid = threadIdx.x;

    // ---- per-sample params (uniform address -> scalar loads) ----
    const float* f = flat + b * 37;
    float Wm[3][3];
#pragma unroll
    for (int d = 0; d < 3; ++d)
#pragma unroll
        for (int c = 0; c < 3; ++c)
            Wm[d][c] = f[d * 3 + c];

    float sh[3];
#pragma unroll
    for (int d = 0; d < 3; ++d) sh[d] = f[9 + d];

    float K[5][5];
#pragma unroll
    for (int i = 0; i < 5; ++i)
#pragma unroll
        for (int j = 0; j < 5; ++j)
            K[i][j] = f[12 + i * 5 + j];

    float bias[3];
#pragma unroll
    for (int c = 0; c < 3; ++c)
        bias[c] = sh[0] * Wm[0][c] + sh[1] * Wm[1][c] + sh[2] * Wm[2][c];

    // ---- stage: global -> (shift + colorwarp) -> LDS, zero outside image ----
    const size_t plane = (size_t)HH * WW;
    const float* im0 = im + (size_t)b * CH * plane;

    for (int idx = tid; idx < HALO_H * HALO_W; idx += 256) {
        const int r  = idx / HALO_W;
        const int cc = idx - r * HALO_W;
        const int gh = th0 + r - 2;
        const int gw = tw0 + cc - 2;
        float o0 = 0.f, o1 = 0.f, o2 = 0.f;
        if ((unsigned)gh < (unsigned)HH && (unsigned)gw < (unsigned)WW) {
            const size_t off = (size_t)gh * WW + gw;
            const float v0 = im0[off];
            const float v1 = im0[plane + off];
            const float v2 = im0[2 * plane + off];
            o0 = v0 * Wm[0][0] + v1 * Wm[1][0] + v2 * Wm[2][0] + bias[0];
            o1 = v0 * Wm[0][1] + v1 * Wm[1][1] + v2 * Wm[2][1] + bias[1];
            o2 = v0 * Wm[0][2] + v1 * Wm[1][2] + v2 * Wm[2][2] + bias[2];
        }
        xs[0][r][cc] = o0;
        xs[1][r][cc] = o1;
        xs[2][r][cc] = o2;
    }
    __syncthreads();

    // ---- conv 5x5 from LDS, register-blocked RX x RY per thread ----
    const int tx = tid & 15;   // 0..15, covers 4 output cols each
    const int ty = tid >> 4;   // 0..15, covers 2 output rows each
    const int r0 = ty * RY;

    float acc[CH][RY][RX];
#pragma unroll
    for (int c = 0; c < CH; ++c)
#pragma unroll
        for (int r = 0; r < RY; ++r)
#pragma unroll
            for (int o = 0; o < RX; ++o)
                acc[c][r][o] = 0.f;

#pragma unroll
    for (int c = 0; c < CH; ++c) {
#pragma unroll
        for (int rr = 0; rr < RY + 4; ++rr) {
            // LDS row r0+rr; cols [tx*4 .. tx*4+7] (16B-aligned: stride 68 floats = 17x16B)
            const float* rowp = &xs[c][r0 + rr][tx * RX];
            const float4 A  = *(const float4*)(rowp);
            const float4 Bv = *(const float4*)(rowp + 4);
            const float w8[8] = {A.x, A.y, A.z, A.w, Bv.x, Bv.y, Bv.z, Bv.w};
#pragma unroll
            for (int i = 0; i < 5; ++i) {
                const int r = rr - i;
                if (r >= 0 && r < RY) {
#pragma unroll
                    for (int j = 0; j < 5; ++j) {
#pragma unroll
                        for (int o = 0; o < RX; ++o)
                            acc[c][r][o] += w8[o + j] * K[i][j];
                    }
                }
            }
        }
    }

    // ---- store: float4 per (c, r) ----
#pragma unroll
    for (int c = 0; c < CH; ++c) {
        float* ob = out + ((size_t)b * CH + c) * plane;
#pragma unroll
        for (int r = 0; r < RY; ++r) {
            const float4 v = make_float4(acc[c][r][0], acc[c][r][1],
                                         acc[c][r][2], acc[c][r][3]);
            *(float4*)&ob[(size_t)(th0 + r0 + r) * WW + tw0 + tx * RX] = v;
        }
    }
}

extern "C" void kernel_launch(void* const* d_in, const int* in_sizes, int n_in,
                              void* d_out, int out_size, void* d_ws, size_t ws_size,
                              hipStream_t stream) {
    const float* im   = (const float*)d_in[0];
    const float* flat = (const float*)d_in[1];
    float* out        = (float*)d_out;

    dim3 grid((WW / TW) * (HH / TH), NB);  // (288, 32)
    colwarp_conv_kernel<<<grid, 256, 0, stream>>>(im, flat, out);
}